// Round 20
// baseline (534.193 us; speedup 1.0000x reference)
//
#include <hip/hip_runtime.h>

#define NN 100000      // nodes
#define NE 400000      // edges per direction
#define NE2 800000
#define C 200          // channels
#define NREL 475       // 2*237 + loop
#define NB 50          // basis
#define NSCAN_BLKS ((2 * NN + 255) / 256)   // 782

// k_pre block-range dispatch
#define NWTB  ((3 * 16 * 7 * 64 + 255) / 256)   // 84
#define NXLB  ((NN * 100 + 255) / 256)          // 39063
#define NDEGB ((NE2 + 255) / 256)               // 3125
#define G_WT    (NREL)                           // 475
#define G_XLOOP (G_WT + NWTB)                    // 559
#define G_DEG   (G_XLOOP + NXLB)                 // 39622
#define NPREB   (G_DEG + NDEGB)                  // 42747

typedef __attribute__((ext_vector_type(8))) short short8;
typedef __attribute__((ext_vector_type(4))) float f32x4;
typedef __attribute__((ext_vector_type(2))) float f32x2;
typedef __attribute__((ext_vector_type(2))) unsigned u32x2;
typedef __attribute__((ext_vector_type(4))) unsigned u32x4;

// workspace layout (u32 word offsets), total ~130 MB
#define W_RE     0L          // 95,000 f32  rel_emb
#define W_DINV   95104L      // 200,000 f32 [dir*NN+node]
#define W_DEG    295104L     // 200,000 int (deg, reused as scatter cursor)
#define W_OFFS   495104L     // 200,001 int CSR offsets
#define W_PSUM   695200L     // 1,024 int
#define W_BUCKET 696320L     // 800,000 u32 packed (tail<<9 | type)
#define W_BNORM  1496320L    // 800,000 f32 per-edge norm (parallel to bucket)
#define W_AGG    2296320L    // (3*NN+128)*100 u32 bf16-pairs: [agg_in | agg_out | x-loop], padded
#define W_WT     32309120L   // 86,016 u32 = 344KB fragment-major bf16 weights
#define W_REB    32395264L   // 47,500 u32 bf16 (re - loop_rel) [475][100]

__device__ __forceinline__ unsigned short f2bf(float f) {
  unsigned u = __builtin_bit_cast(unsigned, f);
  return (unsigned short)((u + 0x7FFFu + ((u >> 16) & 1u)) >> 16);  // RNE
}
__device__ __forceinline__ unsigned pack2(float a, float b) {
  return (unsigned)f2bf(a) | ((unsigned)f2bf(b) << 16);
}
__device__ __forceinline__ float bf_lo(unsigned w) { return __builtin_bit_cast(float, w << 16); }
__device__ __forceinline__ float bf_hi(unsigned w) { return __builtin_bit_cast(float, w & 0xFFFF0000u); }

// ---- fused front-end: {relemb+out2+reb | wt | xloop | deg} by block range ---
// All four bodies VERBATIM from R18; outputs independent; branches block-uniform.

__global__ void k_pre(const float* rw, const float* basis, const float* loop_rel,
                      const float* wrel, float* re, float* out2, unsigned* reb,
                      const float* w_in, const float* w_out, const float* w_loop,
                      short* wtsw, const float* x, unsigned* agg2,
                      const int* ei, int* deg) {
  int b = blockIdx.x;
  int j = threadIdx.x;
  if (b < G_WT) {
    // ---- relemb ----
    __shared__ float srow[C];
    __shared__ float brow[NB];
    int r = b;
    if (j < NB && r < NREL - 1) brow[j] = rw[r * NB + j];
    __syncthreads();
    if (j < C) {
      float v;
      if (r == NREL - 1) {
        v = loop_rel[j];
      } else {
        v = 0.f;
        #pragma unroll 5
        for (int bb = 0; bb < NB; bb++) v += brow[bb] * basis[bb * C + j];
      }
      srow[j] = v;
      re[(size_t)r * C + j] = v;
    }
    __syncthreads();
    if (j < C) {
      float a = 0.f;
      #pragma unroll 4
      for (int k = 0; k < C; k++) a += srow[k] * wrel[k * C + j];
      out2[(size_t)r * C + j] = a;
    }
    if (j < 100) {
      int ch = 2 * j;
      reb[(size_t)r * 100 + j] = pack2(srow[ch] - loop_rel[ch], srow[ch + 1] - loop_rel[ch + 1]);
    }
  } else if (b < G_XLOOP) {
    // ---- wt: fragment-major weights ----
    int i = (b - G_WT) * 256 + j;
    if (i >= 3 * 16 * 7 * 64) return;
    int l = i & 63;
    int rest = i >> 6;
    int ks = rest % 7;
    int rest2 = rest / 7;
    int ct = rest2 & 15;
    int mat = rest2 >> 4;
    const float* W = (mat == 0) ? w_in : (mat == 1) ? w_out : w_loop;
    int n = ct * 16 + (l & 15);
    int kb = ks * 32 + (l >> 4) * 8;
    short8 v;
    #pragma unroll
    for (int q = 0; q < 8; q++) {
      int k = kb + q;
      v[q] = (n < C && k < C) ? (short)f2bf(W[k * C + n]) : (short)0;
    }
    *(short8*)(wtsw + (size_t)i * 8) = v;
  } else if (b < G_DEG) {
    // ---- xloop: agg2 = bf16(x - loop_rel) ----
    int i = (b - G_XLOOP) * 256 + j;
    if (i >= NN * 100) return;
    int n = i / 100, w = i - n * 100;
    int ch = 2 * w;
    f32x2 v = *(const f32x2*)(x + (size_t)n * C + ch);
    f32x2 l = *(const f32x2*)(loop_rel + ch);
    agg2[i] = pack2(v[0] - l[0], v[1] - l[1]);
  } else {
    // ---- deg histogram ----
    int c = (b - G_DEG) * 256 + j;
    if (c >= NE2) return;
    atomicAdd(deg + (c < NE ? 0 : NN) + ei[c], 1);
  }
}

// ---- CSR construction (VERBATIM from R18) -----------------------------------

__global__ void k_scan1(const int* deg, int* psum, float* dinv) {
  __shared__ int s[256];
  int t = threadIdx.x, i = blockIdx.x * 256 + t;
  int v = (i < 2 * NN) ? deg[i] : 0;
  if (i < 2 * NN) dinv[i] = (v > 0) ? rsqrtf((float)v) : 0.f;
  s[t] = v;
  __syncthreads();
  for (int off = 128; off > 0; off >>= 1) {
    if (t < off) s[t] += s[t + off];
    __syncthreads();
  }
  if (t == 0) psum[blockIdx.x] = s[0];
}

__global__ void k_scan2(int* psum) {
  __shared__ int s[1024];
  int t = threadIdx.x;
  int v = (t < NSCAN_BLKS) ? psum[t] : 0;
  s[t] = v;
  __syncthreads();
  for (int off = 1; off < 1024; off <<= 1) {
    int x = (t >= off) ? s[t - off] : 0;
    __syncthreads();
    s[t] += x;
    __syncthreads();
  }
  if (t < NSCAN_BLKS) psum[t] = s[t] - v;  // exclusive
}

__global__ void k_scan3(const int* deg, const int* psum, int* offs, int* cursor) {
  __shared__ int s[256];
  int t = threadIdx.x, i = blockIdx.x * 256 + t;
  int v = (i < 2 * NN) ? deg[i] : 0;
  s[t] = v;
  __syncthreads();
  for (int off = 1; off < 256; off <<= 1) {
    int x = (t >= off) ? s[t - off] : 0;
    __syncthreads();
    s[t] += x;
    __syncthreads();
  }
  if (i < 2 * NN) {
    int o = psum[blockIdx.x] + s[t] - v;
    offs[i] = o;
    cursor[i] = o;
  }
  if (i == 0) offs[2 * NN] = NE2;
}

__global__ void k_scatter(const int* ei, const int* et, const float* dinv,
                          int* cursor, unsigned* bucket, float* bnorm) {
  int c = blockIdx.x * blockDim.x + threadIdx.x;
  if (c >= NE2) return;
  int head = ei[c];
  int tail = ei[NE2 + c];
  int ty = et[c];
  int base = (c < NE) ? 0 : NN;
  float nm = dinv[base + head] * dinv[base + tail];
  int pos = atomicAdd(cursor + base + head, 1);
  bucket[pos] = ((unsigned)tail << 9) | (unsigned)ty;
  bnorm[pos] = nm;
}

// ---- gather -- 4-edge unroll (VERBATIM from R18) ----------------------------

__global__ __launch_bounds__(256) void k_gather(const unsigned* __restrict__ bucket,
                                                const int* __restrict__ offs,
                                                const float* __restrict__ bnorm,
                                                const unsigned* __restrict__ xb,
                                                const unsigned* __restrict__ reb,
                                                unsigned* __restrict__ agg) {
  int wid = (blockIdx.x * blockDim.x + threadIdx.x) >> 6;
  if (wid >= 2 * NN) return;
  int lane = threadIdx.x & 63;
  int s = offs[wid], e = offs[wid + 1];
  bool act = lane < 50;
  int wo = 2 * lane;                 // words wo, wo+1 -> channels 4l..4l+3
  float a0 = 0.f, a1 = 0.f, a2 = 0.f, a3 = 0.f;
  int p = s;
  for (; p + 3 < e; p += 4) {
    unsigned w0 = bucket[p],     w1 = bucket[p + 1];
    unsigned w2 = bucket[p + 2], w3 = bucket[p + 3];
    float n0 = bnorm[p],     n1 = bnorm[p + 1];
    float n2 = bnorm[p + 2], n3 = bnorm[p + 3];
    int t0 = (int)(w0 >> 9), y0 = (int)(w0 & 511u);
    int t1 = (int)(w1 >> 9), y1 = (int)(w1 & 511u);
    int t2 = (int)(w2 >> 9), y2 = (int)(w2 & 511u);
    int t3 = (int)(w3 >> 9), y3 = (int)(w3 & 511u);
    if (act) {
      u32x2 xv0 = *(const u32x2*)(xb + (size_t)t0 * 100 + wo);
      u32x2 rv0 = *(const u32x2*)(reb + (size_t)y0 * 100 + wo);
      u32x2 xv1 = *(const u32x2*)(xb + (size_t)t1 * 100 + wo);
      u32x2 rv1 = *(const u32x2*)(reb + (size_t)y1 * 100 + wo);
      u32x2 xv2 = *(const u32x2*)(xb + (size_t)t2 * 100 + wo);
      u32x2 rv2 = *(const u32x2*)(reb + (size_t)y2 * 100 + wo);
      u32x2 xv3 = *(const u32x2*)(xb + (size_t)t3 * 100 + wo);
      u32x2 rv3 = *(const u32x2*)(reb + (size_t)y3 * 100 + wo);
      a0 += n0 * (bf_lo(xv0[0]) - bf_lo(rv0[0]));
      a1 += n0 * (bf_hi(xv0[0]) - bf_hi(rv0[0]));
      a2 += n0 * (bf_lo(xv0[1]) - bf_lo(rv0[1]));
      a3 += n0 * (bf_hi(xv0[1]) - bf_hi(rv0[1]));
      a0 += n1 * (bf_lo(xv1[0]) - bf_lo(rv1[0]));
      a1 += n1 * (bf_hi(xv1[0]) - bf_hi(rv1[0]));
      a2 += n1 * (bf_lo(xv1[1]) - bf_lo(rv1[1]));
      a3 += n1 * (bf_hi(xv1[1]) - bf_hi(rv1[1]));
      a0 += n2 * (bf_lo(xv2[0]) - bf_lo(rv2[0]));
      a1 += n2 * (bf_hi(xv2[0]) - bf_hi(rv2[0]));
      a2 += n2 * (bf_lo(xv2[1]) - bf_lo(rv2[1]));
      a3 += n2 * (bf_hi(xv2[1]) - bf_hi(rv2[1]));
      a0 += n3 * (bf_lo(xv3[0]) - bf_lo(rv3[0]));
      a1 += n3 * (bf_hi(xv3[0]) - bf_hi(rv3[0]));
      a2 += n3 * (bf_lo(xv3[1]) - bf_lo(rv3[1]));
      a3 += n3 * (bf_hi(xv3[1]) - bf_hi(rv3[1]));
    }
  }
  for (; p < e; ++p) {
    unsigned w0 = bucket[p];
    float n0 = bnorm[p];
    int t0 = (int)(w0 >> 9), y0 = (int)(w0 & 511u);
    if (act) {
      u32x2 xv0 = *(const u32x2*)(xb + (size_t)t0 * 100 + wo);
      u32x2 rv0 = *(const u32x2*)(reb + (size_t)y0 * 100 + wo);
      a0 += n0 * (bf_lo(xv0[0]) - bf_lo(rv0[0]));
      a1 += n0 * (bf_hi(xv0[0]) - bf_hi(rv0[0]));
      a2 += n0 * (bf_lo(xv0[1]) - bf_lo(rv0[1]));
      a3 += n0 * (bf_hi(xv0[1]) - bf_hi(rv0[1]));
    }
  }
  if (act) {
    u32x2 o;
    o[0] = pack2(a0, a1);
    o[1] = pack2(a2, a3);
    *(u32x2*)(agg + (size_t)wid * 100 + wo) = o;
  }
}

// ---- fused triple matmul + tanh (R18 body; DELTA: launch_bounds 4 -> 6) -----
// LDS 26,112 B x 6 blocks = 156.7 KB <= 160 KB/CU; VGPR 64 <= 512/6.

__global__ __launch_bounds__(256, 6) void k_mm(const unsigned* __restrict__ agg,
                                               const short* __restrict__ wt,
                                               float* __restrict__ out) {
  __shared__ __align__(16) unsigned la[6464];   // 64 rows x 100 words + pad
  int tid = threadIdx.x;
  int wave = tid >> 6;
  int lane = tid & 63;
  int m = lane & 15, kq = lane >> 4;
  int row0 = blockIdx.x * 64;
  int cw = (wave + blockIdx.x) & 3;   // rotated column-quadrant ownership

  f32x4 acc[4][4];
  #pragma unroll
  for (int s = 0; s < 4; s++)
    #pragma unroll
    for (int t = 0; t < 4; t++) acc[s][t] = (f32x4)(0.f);

  for (int mat = 0; mat < 3; mat++) {
    __syncthreads();   // previous mat's LDS reads complete
    const u32x4* src = (const u32x4*)(agg + ((size_t)mat * NN + row0) * 100);
    for (int idx = tid; idx < 1600; idx += 256)
      ((u32x4*)la)[idx] = src[idx];
    if (tid < 64) la[6400 + tid] = 0;     // pad (read by ks=6,kq>0; x0 weight)
    __syncthreads();   // staging complete

    #pragma unroll
    for (int ks = 0; ks < 7; ks++) {
      short8 A[4], B[4];
      #pragma unroll
      for (int s = 0; s < 4; s++)
        A[s] = *(const short8*)(la + (size_t)(s * 16 + m) * 100 + kq * 4 + ks * 16);
      #pragma unroll
      for (int t = 0; t < 4; t++) {
        int g = cw * 4 + t;
        if (g < 13)
          B[t] = *(const short8*)(wt + ((size_t)((mat * 16 + g) * 7 + ks) * 64 + lane) * 8);
      }
      #pragma unroll
      for (int s = 0; s < 4; s++)
        #pragma unroll
        for (int t = 0; t < 4; t++)
          if (cw * 4 + t < 13)
            acc[s][t] = __builtin_amdgcn_mfma_f32_16x16x32_bf16(A[s], B[t], acc[s][t], 0, 0, 0);
    }
  }

  #pragma unroll
  for (int s = 0; s < 4; s++) {
    int r0 = row0 + s * 16 + kq * 4;   // D: col = lane&15, row = 4*kq + reg
    #pragma unroll
    for (int t = 0; t < 4; t++) {
      int n = cw * 64 + t * 16 + m;
      if (n >= C) continue;
      #pragma unroll
      for (int j = 0; j < 4; j++) {
        int r = r0 + j;
        if (r < NN)
          __builtin_nontemporal_store(tanhf(acc[s][t][j] * (1.f / 3.f)),
                                      &out[(size_t)r * C + n]);
      }
    }
  }
}

// -----------------------------------------------------------------------------

extern "C" void kernel_launch(void* const* d_in, const int* in_sizes, int n_in,
                              void* d_out, int out_size, void* d_ws, size_t ws_size,
                              hipStream_t stream) {
  const float* X        = (const float*)d_in[0];
  const int*   ei       = (const int*)d_in[1];
  const int*   et       = (const int*)d_in[2];
  const float* basis    = (const float*)d_in[3];
  const float* relw     = (const float*)d_in[4];
  const float* wrel     = (const float*)d_in[5];
  const float* loop_rel = (const float*)d_in[6];
  const float* w_in     = (const float*)d_in[7];
  const float* w_out    = (const float*)d_in[8];
  const float* w_loop   = (const float*)d_in[9];

  float* out = (float*)d_out;
  float* ws  = (float*)d_ws;

  float*    re     = ws + W_RE;
  float*    dinv   = ws + W_DINV;
  int*      deg    = (int*)(ws + W_DEG);     // reused as scatter cursor
  int*      offs   = (int*)(ws + W_OFFS);
  int*      psum   = (int*)(ws + W_PSUM);
  unsigned* bucket = (unsigned*)(ws + W_BUCKET);
  float*    bnorm  = ws + W_BNORM;
  unsigned* agg    = (unsigned*)(ws + W_AGG);
  short*    wt     = (short*)(ws + W_WT);
  unsigned* reb    = (unsigned*)(ws + W_REB);
  float*    out2   = out + (size_t)NN * C;
  unsigned* agg2   = agg + (size_t)2 * NN * 100;

  hipMemsetAsync(deg, 0, 2 * NN * sizeof(int), stream);

  k_pre<<<NPREB, 256, 0, stream>>>(relw, basis, loop_rel, wrel, re, out2, reb,
                                   w_in, w_out, w_loop, wt, X, agg2, ei, deg);

  k_scan1<<<NSCAN_BLKS, 256, 0, stream>>>(deg, psum, dinv);
  k_scan2<<<1, 1024, 0, stream>>>(psum);
  k_scan3<<<NSCAN_BLKS, 256, 0, stream>>>(deg, psum, offs, deg /*cursor*/);
  k_scatter<<<(NE2 + 255) / 256, 256, 0, stream>>>(ei, et, dinv, deg /*cursor*/, bucket, bnorm);

  k_gather<<<(2 * NN) / 4, 256, 0, stream>>>(bucket, offs, bnorm, agg2, reb, agg);
  k_mm<<<(NN + 63) / 64, 256, 0, stream>>>(agg, wt, out);
}

// Round 21
// 294.659 us; speedup vs baseline: 1.8129x; 1.8129x over previous
//
#include <hip/hip_runtime.h>

#define NN 100000      // nodes
#define NE 400000      // edges per direction
#define NE2 800000
#define C 200          // channels
#define NREL 475       // 2*237 + loop
#define NB 50          // basis
#define NSCAN_BLKS ((2 * NN + 255) / 256)   // 782

// k_pre block-range dispatch
#define NWTB  ((3 * 16 * 7 * 64 + 255) / 256)   // 84
#define NXLB  ((NN * 100 + 255) / 256)          // 39063
#define NDEGB ((NE2 + 255) / 256)               // 3125
#define G_WT    (NREL)                           // 475
#define G_XLOOP (G_WT + NWTB)                    // 559
#define G_DEG   (G_XLOOP + NXLB)                 // 39622
#define NPREB   (G_DEG + NDEGB)                  // 42747

typedef __attribute__((ext_vector_type(8))) short short8;
typedef __attribute__((ext_vector_type(4))) float f32x4;
typedef __attribute__((ext_vector_type(2))) float f32x2;
typedef __attribute__((ext_vector_type(2))) unsigned u32x2;
typedef __attribute__((ext_vector_type(4))) unsigned u32x4;

// workspace layout (u32 word offsets), total ~130 MB
#define W_RE     0L          // 95,000 f32  rel_emb
#define W_DINV   95104L      // 200,000 f32 [dir*NN+node]
#define W_DEG    295104L     // 200,000 int (deg, reused as scatter cursor)
#define W_OFFS   495104L     // 200,001 int CSR offsets
#define W_PSUM   695200L     // 1,024 int
#define W_BUCKET 696320L     // 800,000 u32 packed (tail<<9 | type)
#define W_BNORM  1496320L    // 800,000 f32 per-edge norm (parallel to bucket)
#define W_AGG    2296320L    // (3*NN+128)*100 u32 bf16-pairs: [agg_in | agg_out | x-loop], padded
#define W_WT     32309120L   // 86,016 u32 = 344KB fragment-major bf16 weights
#define W_REB    32395264L   // 47,500 u32 bf16 (re - loop_rel) [475][100]

__device__ __forceinline__ unsigned short f2bf(float f) {
  unsigned u = __builtin_bit_cast(unsigned, f);
  return (unsigned short)((u + 0x7FFFu + ((u >> 16) & 1u)) >> 16);  // RNE
}
__device__ __forceinline__ unsigned pack2(float a, float b) {
  return (unsigned)f2bf(a) | ((unsigned)f2bf(b) << 16);
}
__device__ __forceinline__ float bf_lo(unsigned w) { return __builtin_bit_cast(float, w << 16); }
__device__ __forceinline__ float bf_hi(unsigned w) { return __builtin_bit_cast(float, w & 0xFFFF0000u); }

// ---- fused front-end: {relemb+out2+reb | wt | xloop | deg} by block range ---

__global__ void k_pre(const float* rw, const float* basis, const float* loop_rel,
                      const float* wrel, float* re, float* out2, unsigned* reb,
                      const float* w_in, const float* w_out, const float* w_loop,
                      short* wtsw, const float* x, unsigned* agg2,
                      const int* ei, int* deg) {
  int b = blockIdx.x;
  int j = threadIdx.x;
  if (b < G_WT) {
    // ---- relemb ----
    __shared__ float srow[C];
    __shared__ float brow[NB];
    int r = b;
    if (j < NB && r < NREL - 1) brow[j] = rw[r * NB + j];
    __syncthreads();
    if (j < C) {
      float v;
      if (r == NREL - 1) {
        v = loop_rel[j];
      } else {
        v = 0.f;
        #pragma unroll 5
        for (int bb = 0; bb < NB; bb++) v += brow[bb] * basis[bb * C + j];
      }
      srow[j] = v;
      re[(size_t)r * C + j] = v;
    }
    __syncthreads();
    if (j < C) {
      float a = 0.f;
      #pragma unroll 4
      for (int k = 0; k < C; k++) a += srow[k] * wrel[k * C + j];
      out2[(size_t)r * C + j] = a;
    }
    if (j < 100) {
      int ch = 2 * j;
      reb[(size_t)r * 100 + j] = pack2(srow[ch] - loop_rel[ch], srow[ch + 1] - loop_rel[ch + 1]);
    }
  } else if (b < G_XLOOP) {
    // ---- wt: fragment-major weights ----
    int i = (b - G_WT) * 256 + j;
    if (i >= 3 * 16 * 7 * 64) return;
    int l = i & 63;
    int rest = i >> 6;
    int ks = rest % 7;
    int rest2 = rest / 7;
    int ct = rest2 & 15;
    int mat = rest2 >> 4;
    const float* W = (mat == 0) ? w_in : (mat == 1) ? w_out : w_loop;
    int n = ct * 16 + (l & 15);
    int kb = ks * 32 + (l >> 4) * 8;
    short8 v;
    #pragma unroll
    for (int q = 0; q < 8; q++) {
      int k = kb + q;
      v[q] = (n < C && k < C) ? (short)f2bf(W[k * C + n]) : (short)0;
    }
    *(short8*)(wtsw + (size_t)i * 8) = v;
  } else if (b < G_DEG) {
    // ---- xloop: agg2 = bf16(x - loop_rel) ----
    int i = (b - G_XLOOP) * 256 + j;
    if (i >= NN * 100) return;
    int n = i / 100, w = i - n * 100;
    int ch = 2 * w;
    f32x2 v = *(const f32x2*)(x + (size_t)n * C + ch);
    f32x2 l = *(const f32x2*)(loop_rel + ch);
    agg2[i] = pack2(v[0] - l[0], v[1] - l[1]);
  } else {
    // ---- deg histogram ----
    int c = (b - G_DEG) * 256 + j;
    if (c >= NE2) return;
    atomicAdd(deg + (c < NE ? 0 : NN) + ei[c], 1);
  }
}

// ---- CSR construction -------------------------------------------------------

__global__ void k_scan1(const int* deg, int* psum, float* dinv) {
  __shared__ int s[256];
  int t = threadIdx.x, i = blockIdx.x * 256 + t;
  int v = (i < 2 * NN) ? deg[i] : 0;
  if (i < 2 * NN) dinv[i] = (v > 0) ? rsqrtf((float)v) : 0.f;
  s[t] = v;
  __syncthreads();
  for (int off = 128; off > 0; off >>= 1) {
    if (t < off) s[t] += s[t + off];
    __syncthreads();
  }
  if (t == 0) psum[blockIdx.x] = s[0];
}

__global__ void k_scan2(int* psum) {
  __shared__ int s[1024];
  int t = threadIdx.x;
  int v = (t < NSCAN_BLKS) ? psum[t] : 0;
  s[t] = v;
  __syncthreads();
  for (int off = 1; off < 1024; off <<= 1) {
    int x = (t >= off) ? s[t - off] : 0;
    __syncthreads();
    s[t] += x;
    __syncthreads();
  }
  if (t < NSCAN_BLKS) psum[t] = s[t] - v;  // exclusive
}

__global__ void k_scan3(const int* deg, const int* psum, int* offs, int* cursor) {
  __shared__ int s[256];
  int t = threadIdx.x, i = blockIdx.x * 256 + t;
  int v = (i < 2 * NN) ? deg[i] : 0;
  s[t] = v;
  __syncthreads();
  for (int off = 1; off < 256; off <<= 1) {
    int x = (t >= off) ? s[t - off] : 0;
    __syncthreads();
    s[t] += x;
    __syncthreads();
  }
  if (i < 2 * NN) {
    int o = psum[blockIdx.x] + s[t] - v;
    offs[i] = o;
    cursor[i] = o;
  }
  if (i == 0) offs[2 * NN] = NE2;
}

__global__ void k_scatter(const int* ei, const int* et, const float* dinv,
                          int* cursor, unsigned* bucket, float* bnorm) {
  int c = blockIdx.x * blockDim.x + threadIdx.x;
  if (c >= NE2) return;
  int head = ei[c];
  int tail = ei[NE2 + c];
  int ty = et[c];
  int base = (c < NE) ? 0 : NN;
  float nm = dinv[base + head] * dinv[base + tail];
  int pos = atomicAdd(cursor + base + head, 1);
  bucket[pos] = ((unsigned)tail << 9) | (unsigned)ty;
  bnorm[pos] = nm;
}

// ---- gather -- 4-edge unroll ------------------------------------------------

__global__ __launch_bounds__(256) void k_gather(const unsigned* __restrict__ bucket,
                                                const int* __restrict__ offs,
                                                const float* __restrict__ bnorm,
                                                const unsigned* __restrict__ xb,
                                                const unsigned* __restrict__ reb,
                                                unsigned* __restrict__ agg) {
  int wid = (blockIdx.x * blockDim.x + threadIdx.x) >> 6;
  if (wid >= 2 * NN) return;
  int lane = threadIdx.x & 63;
  int s = offs[wid], e = offs[wid + 1];
  bool act = lane < 50;
  int wo = 2 * lane;                 // words wo, wo+1 -> channels 4l..4l+3
  float a0 = 0.f, a1 = 0.f, a2 = 0.f, a3 = 0.f;
  int p = s;
  for (; p + 3 < e; p += 4) {
    unsigned w0 = bucket[p],     w1 = bucket[p + 1];
    unsigned w2 = bucket[p + 2], w3 = bucket[p + 3];
    float n0 = bnorm[p],     n1 = bnorm[p + 1];
    float n2 = bnorm[p + 2], n3 = bnorm[p + 3];
    int t0 = (int)(w0 >> 9), y0 = (int)(w0 & 511u);
    int t1 = (int)(w1 >> 9), y1 = (int)(w1 & 511u);
    int t2 = (int)(w2 >> 9), y2 = (int)(w2 & 511u);
    int t3 = (int)(w3 >> 9), y3 = (int)(w3 & 511u);
    if (act) {
      u32x2 xv0 = *(const u32x2*)(xb + (size_t)t0 * 100 + wo);
      u32x2 rv0 = *(const u32x2*)(reb + (size_t)y0 * 100 + wo);
      u32x2 xv1 = *(const u32x2*)(xb + (size_t)t1 * 100 + wo);
      u32x2 rv1 = *(const u32x2*)(reb + (size_t)y1 * 100 + wo);
      u32x2 xv2 = *(const u32x2*)(xb + (size_t)t2 * 100 + wo);
      u32x2 rv2 = *(const u32x2*)(reb + (size_t)y2 * 100 + wo);
      u32x2 xv3 = *(const u32x2*)(xb + (size_t)t3 * 100 + wo);
      u32x2 rv3 = *(const u32x2*)(reb + (size_t)y3 * 100 + wo);
      a0 += n0 * (bf_lo(xv0[0]) - bf_lo(rv0[0]));
      a1 += n0 * (bf_hi(xv0[0]) - bf_hi(rv0[0]));
      a2 += n0 * (bf_lo(xv0[1]) - bf_lo(rv0[1]));
      a3 += n0 * (bf_hi(xv0[1]) - bf_hi(rv0[1]));
      a0 += n1 * (bf_lo(xv1[0]) - bf_lo(rv1[0]));
      a1 += n1 * (bf_hi(xv1[0]) - bf_hi(rv1[0]));
      a2 += n1 * (bf_lo(xv1[1]) - bf_lo(rv1[1]));
      a3 += n1 * (bf_hi(xv1[1]) - bf_hi(rv1[1]));
      a0 += n2 * (bf_lo(xv2[0]) - bf_lo(rv2[0]));
      a1 += n2 * (bf_hi(xv2[0]) - bf_hi(rv2[0]));
      a2 += n2 * (bf_lo(xv2[1]) - bf_lo(rv2[1]));
      a3 += n2 * (bf_hi(xv2[1]) - bf_hi(rv2[1]));
      a0 += n3 * (bf_lo(xv3[0]) - bf_lo(rv3[0]));
      a1 += n3 * (bf_hi(xv3[0]) - bf_hi(rv3[0]));
      a2 += n3 * (bf_lo(xv3[1]) - bf_lo(rv3[1]));
      a3 += n3 * (bf_hi(xv3[1]) - bf_hi(rv3[1]));
    }
  }
  for (; p < e; ++p) {
    unsigned w0 = bucket[p];
    float n0 = bnorm[p];
    int t0 = (int)(w0 >> 9), y0 = (int)(w0 & 511u);
    if (act) {
      u32x2 xv0 = *(const u32x2*)(xb + (size_t)t0 * 100 + wo);
      u32x2 rv0 = *(const u32x2*)(reb + (size_t)y0 * 100 + wo);
      a0 += n0 * (bf_lo(xv0[0]) - bf_lo(rv0[0]));
      a1 += n0 * (bf_hi(xv0[0]) - bf_hi(rv0[0]));
      a2 += n0 * (bf_lo(xv0[1]) - bf_lo(rv0[1]));
      a3 += n0 * (bf_hi(xv0[1]) - bf_hi(rv0[1]));
    }
  }
  if (act) {
    u32x2 o;
    o[0] = pack2(a0, a1);
    o[1] = pack2(a2, a3);
    *(u32x2*)(agg + (size_t)wid * 100 + wo) = o;
  }
}

// ---- fused triple matmul + tanh (R18: LDS-staged A, fragment-major B,
// dead-tile skip, bound (256,4) = exactly the 128-reg/thread budget) ----------

__global__ __launch_bounds__(256, 4) void k_mm(const unsigned* __restrict__ agg,
                                               const short* __restrict__ wt,
                                               float* __restrict__ out) {
  __shared__ __align__(16) unsigned la[6464];   // 64 rows x 100 words + pad
  int tid = threadIdx.x;
  int wave = tid >> 6;
  int lane = tid & 63;
  int m = lane & 15, kq = lane >> 4;
  int row0 = blockIdx.x * 64;
  int cw = (wave + blockIdx.x) & 3;   // rotated column-quadrant ownership

  f32x4 acc[4][4];
  #pragma unroll
  for (int s = 0; s < 4; s++)
    #pragma unroll
    for (int t = 0; t < 4; t++) acc[s][t] = (f32x4)(0.f);

  for (int mat = 0; mat < 3; mat++) {
    __syncthreads();   // previous mat's LDS reads complete
    const u32x4* src = (const u32x4*)(agg + ((size_t)mat * NN + row0) * 100);
    for (int idx = tid; idx < 1600; idx += 256)
      ((u32x4*)la)[idx] = src[idx];
    if (tid < 64) la[6400 + tid] = 0;     // pad (read by ks=6,kq>0; x0 weight)
    __syncthreads();   // staging complete

    #pragma unroll
    for (int ks = 0; ks < 7; ks++) {
      short8 A[4], B[4];
      #pragma unroll
      for (int s = 0; s < 4; s++)
        A[s] = *(const short8*)(la + (size_t)(s * 16 + m) * 100 + kq * 4 + ks * 16);
      #pragma unroll
      for (int t = 0; t < 4; t++) {
        int g = cw * 4 + t;
        if (g < 13)
          B[t] = *(const short8*)(wt + ((size_t)((mat * 16 + g) * 7 + ks) * 64 + lane) * 8);
      }
      #pragma unroll
      for (int s = 0; s < 4; s++)
        #pragma unroll
        for (int t = 0; t < 4; t++)
          if (cw * 4 + t < 13)
            acc[s][t] = __builtin_amdgcn_mfma_f32_16x16x32_bf16(A[s], B[t], acc[s][t], 0, 0, 0);
    }
  }

  #pragma unroll
  for (int s = 0; s < 4; s++) {
    int r0 = row0 + s * 16 + kq * 4;   // D: col = lane&15, row = 4*kq + reg
    #pragma unroll
    for (int t = 0; t < 4; t++) {
      int n = cw * 64 + t * 16 + m;
      if (n >= C) continue;
      #pragma unroll
      for (int j = 0; j < 4; j++) {
        int r = r0 + j;
        if (r < NN)
          __builtin_nontemporal_store(tanhf(acc[s][t][j] * (1.f / 3.f)),
                                      &out[(size_t)r * C + n]);
      }
    }
  }
}

// -----------------------------------------------------------------------------

extern "C" void kernel_launch(void* const* d_in, const int* in_sizes, int n_in,
                              void* d_out, int out_size, void* d_ws, size_t ws_size,
                              hipStream_t stream) {
  const float* X        = (const float*)d_in[0];
  const int*   ei       = (const int*)d_in[1];
  const int*   et       = (const int*)d_in[2];
  const float* basis    = (const float*)d_in[3];
  const float* relw     = (const float*)d_in[4];
  const float* wrel     = (const float*)d_in[5];
  const float* loop_rel = (const float*)d_in[6];
  const float* w_in     = (const float*)d_in[7];
  const float* w_out    = (const float*)d_in[8];
  const float* w_loop   = (const float*)d_in[9];

  float* out = (float*)d_out;
  float* ws  = (float*)d_ws;

  float*    re     = ws + W_RE;
  float*    dinv   = ws + W_DINV;
  int*      deg    = (int*)(ws + W_DEG);     // reused as scatter cursor
  int*      offs   = (int*)(ws + W_OFFS);
  int*      psum   = (int*)(ws + W_PSUM);
  unsigned* bucket = (unsigned*)(ws + W_BUCKET);
  float*    bnorm  = ws + W_BNORM;
  unsigned* agg    = (unsigned*)(ws + W_AGG);
  short*    wt     = (short*)(ws + W_WT);
  unsigned* reb    = (unsigned*)(ws + W_REB);
  float*    out2   = out + (size_t)NN * C;
  unsigned* agg2   = agg + (size_t)2 * NN * 100;

  hipMemsetAsync(deg, 0, 2 * NN * sizeof(int), stream);

  k_pre<<<NPREB, 256, 0, stream>>>(relw, basis, loop_rel, wrel, re, out2, reb,
                                   w_in, w_out, w_loop, wt, X, agg2, ei, deg);

  k_scan1<<<NSCAN_BLKS, 256, 0, stream>>>(deg, psum, dinv);
  k_scan2<<<1, 1024, 0, stream>>>(psum);
  k_scan3<<<NSCAN_BLKS, 256, 0, stream>>>(deg, psum, offs, deg /*cursor*/);
  k_scatter<<<(NE2 + 255) / 256, 256, 0, stream>>>(ei, et, dinv, deg /*cursor*/, bucket, bnorm);

  k_gather<<<(2 * NN) / 4, 256, 0, stream>>>(bucket, offs, bnorm, agg2, reb, agg);
  k_mm<<<(NN + 63) / 64, 256, 0, stream>>>(agg, wt, out);
}